// Round 5
// baseline (353.258 us; speedup 1.0000x reference)
//
#include <hip/hip_runtime.h>
#include <hip/hip_bf16.h>
#include <stdint.h>
#include <stddef.h>

typedef __hip_bfloat16 bf16_t;
typedef __attribute__((ext_vector_type(8))) short short8;
typedef __attribute__((ext_vector_type(4))) short short4v;
typedef __attribute__((ext_vector_type(4))) float floatx4;

#define EMBED 1024
#define NHEAD 16
#define HDIM  64
#define BATCH 2
#define SEQ   2048
#define MTOT  (BATCH*SEQ)
#define NEG_INF (-1e30f)
#define QSCALE 0.1803368801111244f   // 0.125 * log2(e): S emerges in exp2 domain

#define MFMA16(a,b,c) __builtin_amdgcn_mfma_f32_16x16x32_bf16(a,b,c,0,0,0)

static __device__ __forceinline__ short bf16_bits(float x) {
    return __builtin_bit_cast(short, __float2bfloat16(x));
}

// async global->LDS, 16B per lane; lds ptr must be wave-uniform (HW: base + lane*16)
static __device__ __forceinline__ void async_ld16(const bf16_t* g, short* l) {
    __builtin_amdgcn_global_load_lds(
        (const __attribute__((address_space(1))) void*)g,
        (__attribute__((address_space(3))) void*)l,
        16, 0, 0);
}

static __device__ __forceinline__ void store_out(float* p, float v)  { *p = v; }
static __device__ __forceinline__ void store_out(bf16_t* p, float v) { *p = __float2bfloat16(v); }

// fp32 -> bf16 (RTNE) for q,k,v (4M each) and Wq,Wk,Wv,Wo (1M each). grid.y selects tensor.
__global__ __launch_bounds__(256)
void cvt_all(const float* __restrict__ q, const float* __restrict__ k, const float* __restrict__ v,
             const float* __restrict__ wq, const float* __restrict__ wk,
             const float* __restrict__ wv, const float* __restrict__ wo,
             bf16_t* __restrict__ Qx, bf16_t* __restrict__ Kx, bf16_t* __restrict__ Vx,
             bf16_t* __restrict__ Wqb, bf16_t* __restrict__ Wkb,
             bf16_t* __restrict__ Wvb, bf16_t* __restrict__ Wob)
{
    const float* s; bf16_t* d; int n;
    switch (blockIdx.y) {
        case 0:  s = q;  d = Qx;  n = MTOT * EMBED;  break;
        case 1:  s = k;  d = Kx;  n = MTOT * EMBED;  break;
        case 2:  s = v;  d = Vx;  n = MTOT * EMBED;  break;
        case 3:  s = wq; d = Wqb; n = EMBED * EMBED; break;
        case 4:  s = wk; d = Wkb; n = EMBED * EMBED; break;
        case 5:  s = wv; d = Wvb; n = EMBED * EMBED; break;
        default: s = wo; d = Wob; n = EMBED * EMBED; break;
    }
    const int i4 = (int)blockIdx.x * 256 + (int)threadIdx.x;   // float4 index
    if (i4 * 4 < n) {
        const float4 f = ((const float4*)s)[i4];
        short4v o;
        o[0] = bf16_bits(f.x); o[1] = bf16_bits(f.y);
        o[2] = bf16_bits(f.z); o[3] = bf16_bits(f.w);
        ((short4v*)d)[i4] = o;
    }
}

// C[M,N] = A[M,K] @ W[N,K]^T + bias, bf16 in, fp32 accumulate, output scaled by oscale.
// M=4096, N=K=1024 fixed. 128x128 tile, BK=32, 256 thr (4 waves 2x2). m97 structure.
// VT=true: write output transposed per-batch as Ct[b*1024 + n][s].
template <typename OutT, bool VT>
static __device__ __forceinline__ void gemm_tile_128(
    const bf16_t* __restrict__ A, const bf16_t* __restrict__ W,
    const float* __restrict__ bias, OutT* __restrict__ C, float oscale)
{
    const int N = 1024, K = 1024;
    __shared__ alignas(16) short As[128*32];
    __shared__ alignas(16) short Bs[128*32];

    const int tid  = threadIdx.x;
    const int wave = tid >> 6;
    const int lane = tid & 63;
    const int nbn = N >> 7;                 // 8
    const int bm = (int)blockIdx.x / nbn;
    const int bn = (int)blockIdx.x % nbn;
    const int m0 = bm << 7, n0 = bn << 7;

    const int wm = ((wave >> 1) & 1) << 6;  // 0 / 64
    const int wn = (wave & 1) << 6;

    floatx4 acc[4][4] = {};

    const int srow = (wave << 5) + (lane >> 2);   // staging row within tile
    const int scol = (lane & 3) << 3;             // element col: 0,8,16,24
    const bf16_t* gA = A + (size_t)(m0 + srow) * K + scol;
    const bf16_t* gB = W + (size_t)(n0 + srow) * K + scol;
    short* lA0 = &As[(wave << 10)];
    short* lA1 = &As[(wave << 10) + 512];
    short* lB0 = &Bs[(wave << 10)];
    short* lB1 = &Bs[(wave << 10) + 512];

    const int fr = lane & 15;
    const int fk = (lane >> 4) << 3;

    for (int k0 = 0; k0 < K; k0 += 32) {
        __syncthreads();
        async_ld16(gA,                  lA0);
        async_ld16(gA + (size_t)16 * K, lA1);
        async_ld16(gB,                  lB0);
        async_ld16(gB + (size_t)16 * K, lB1);
        gA += 32; gB += 32;
        __syncthreads();                      // drains vmcnt before barrier (m97-verified)

        short8 af[4], bfr[4];
        #pragma unroll
        for (int i = 0; i < 4; ++i)
            af[i] = *(const short8*)&As[(wm + (i << 4) + fr) * 32 + fk];
        #pragma unroll
        for (int j = 0; j < 4; ++j)
            bfr[j] = *(const short8*)&Bs[(wn + (j << 4) + fr) * 32 + fk];
        #pragma unroll
        for (int i = 0; i < 4; ++i)
            #pragma unroll
            for (int j = 0; j < 4; ++j)
                acc[i][j] = MFMA16(af[i], bfr[j], acc[i][j]);
    }

    // epilogue: C/D layout col=lane&15, row=quad*4+r
    const int q4 = (lane >> 4) << 2;
    #pragma unroll
    for (int j = 0; j < 4; ++j) {
        const int n = n0 + wn + (j << 4) + fr;
        const float bv = bias[n];
        #pragma unroll
        for (int i = 0; i < 4; ++i) {
            const int mb = m0 + wm + (i << 4) + q4;
            if (VT) {
                const int bb = mb >> 11, ss = mb & 2047;
                short4v pk;
                #pragma unroll
                for (int r = 0; r < 4; ++r)
                    pk[r] = bf16_bits((acc[i][j][r] + bv) * oscale);
                *(short4v*)((bf16_t*)C + ((size_t)(bb * 1024 + n) << 11) + ss) = pk;
            } else {
                #pragma unroll
                for (int r = 0; r < 4; ++r)
                    store_out(&C[(size_t)(mb + r) * N + n], (acc[i][j][r] + bv) * oscale);
            }
        }
    }
}

__global__ __launch_bounds__(256)
void qkv_proj(const bf16_t* __restrict__ xq, const bf16_t* __restrict__ xk,
              const bf16_t* __restrict__ xv,
              const bf16_t* __restrict__ Wq, const bf16_t* __restrict__ Wk,
              const bf16_t* __restrict__ Wv,
              const float* __restrict__ bq, const float* __restrict__ bk,
              const float* __restrict__ bv,
              bf16_t* __restrict__ Qp, bf16_t* __restrict__ Kp, bf16_t* __restrict__ Vtp)
{
    if (blockIdx.z == 0)      gemm_tile_128<bf16_t, false>(xq, Wq, bq, Qp, QSCALE);  // Q pre-scaled
    else if (blockIdx.z == 1) gemm_tile_128<bf16_t, false>(xk, Wk, bk, Kp, 1.0f);
    else                      gemm_tile_128<bf16_t, true >(xv, Wv, bv, Vtp, 1.0f);
}

__global__ __launch_bounds__(256)
void out_proj(const bf16_t* __restrict__ AO, const bf16_t* __restrict__ Wo,
              const float* __restrict__ bo, float* __restrict__ out)
{
    gemm_tile_128<float, false>(AO, Wo, bo, out, 1.0f);
}

// Flash attention, causal. S^T (D = K·Q^T) AND O^T (D = V^T·P^T) formulations:
// one q-row per lane (q = lane&15) for both softmax state and O accumulator ->
// alpha/l are lane-scalars, zero cross-lane ops for them. P round-trips through
// wave-local LDS in [16 q][stride 40] layout: write pattern = S^T C-layout, read
// pattern = B-frag; stride 40 shorts (80 B) makes both accesses bank-conflict-free.
// Dual streams (even/odd chunks, independent m/l/O, merged at end) for ILP.
// No barriers, no fences; same-wave DS ops are in-order, same-array short* accesses
// keep compiler order. Q arrives pre-scaled by 0.125*log2e -> exp2-domain softmax.
__global__ __launch_bounds__(256)
void attn_causal(const bf16_t* __restrict__ Qp, const bf16_t* __restrict__ Kp,
                 const bf16_t* __restrict__ Vt, bf16_t* __restrict__ AO)
{
    __shared__ alignas(16) short Pbuf[8][16 * 40];   // 2 streams x 4 waves, 1280 B each

    const int tid  = threadIdx.x;
    const int wave = tid >> 6;
    const int lane = tid & 63;
    const int g  = (int)blockIdx.x & 31;
    const int bh = (int)blockIdx.x >> 5;          // 0..31
    const int b  = bh >> 4, h = bh & 15;
    // static balance: block's 4 waves take tiles {g, g+32, 95-g, 127-g} -> 130 chunks/block
    const int t4 = (wave == 0) ? g : (wave == 1) ? (32 + g) : (wave == 2) ? (95 - g) : (127 - g);
    const int q0 = t4 << 4;

    const int fr   = lane & 15;
    const int quad = lane >> 4;
    const int fk   = quad << 3;

    // Q B-frags (B[k=d][n=q]): lane holds Q[q0+fr][fk+j] (+32)
    const bf16_t* Qrow = Qp + (size_t)(b * SEQ + q0 + fr) * EMBED + h * HDIM;
    const short8 aq0 = *(const short8*)(Qrow + fk);
    const short8 aq1 = *(const short8*)(Qrow + 32 + fk);

    const bf16_t* Kbase = Kp + (size_t)(b * SEQ) * EMBED + h * HDIM;
    const bf16_t* Vbase = Vt + ((size_t)(b * 1024 + h * HDIM) << 11);

    floatx4 oA[4] = {}, oB[4] = {};          // O^T[d=t*16+quad*4+r][q=fr]
    float mA = NEG_INF, lA = 0.f;
    float mB = NEG_INF, lB = 0.f;

    short* PwA = &Pbuf[wave * 2][0];
    short* PwB = &Pbuf[wave * 2 + 1][0];

    const int nfull = q0 >> 5;               // fully-unmasked 32-kv chunks; then 1 masked

    auto chunk = [&](int kv0, float& m, float& l, floatx4* o, short* Pw, bool masked) {
        // K A-frags (A[m=kv][k=d]): lane holds K[kv0+(sub*16)+fr][fk+j]
        const bf16_t* Kr0 = Kbase + (size_t)(kv0 + fr) * EMBED;
        const bf16_t* Kr1 = Kr0 + (size_t)16 * EMBED;
        const short8 k00 = *(const short8*)(Kr0 + fk);
        const short8 k01 = *(const short8*)(Kr0 + 32 + fk);
        const short8 k10 = *(const short8*)(Kr1 + fk);
        const short8 k11 = *(const short8*)(Kr1 + 32 + fk);

        floatx4 s0 = {}, s1 = {};
        s0 = MFMA16(k00, aq0, s0);
        s0 = MFMA16(k01, aq1, s0);
        s1 = MFMA16(k10, aq0, s1);
        s1 = MFMA16(k11, aq1, s1);

        // S^T layout: lane holds S[kv0 + quad*4+r (+16)][q0+fr], already in exp2 domain
        float v0[4], v1[4], mx = NEG_INF;
        #pragma unroll
        for (int r = 0; r < 4; ++r) {
            float a = s0[r], bb = s1[r];
            if (masked) {
                const int q = q0 + fr, kva = kv0 + (quad << 2) + r;
                if (kva > q)      a  = NEG_INF;
                if (kva + 16 > q) bb = NEG_INF;
            }
            v0[r] = a; v1[r] = bb;
            mx = fmaxf(mx, fmaxf(a, bb));
        }
        mx = fmaxf(mx, __shfl_xor(mx, 16, 64));
        mx = fmaxf(mx, __shfl_xor(mx, 32, 64));

        const float mnew = fmaxf(m, mx);
        const float al = __builtin_amdgcn_exp2f(m - mnew);
        m = mnew;
        float ls = 0.f;
        #pragma unroll
        for (int r = 0; r < 4; ++r) {
            v0[r] = __builtin_amdgcn_exp2f(v0[r] - mnew);
            v1[r] = __builtin_amdgcn_exp2f(v1[r] - mnew);
            ls += v0[r] + v1[r];
        }
        ls += __shfl_xor(ls, 16, 64);
        ls += __shfl_xor(ls, 32, 64);
        l = l * al + ls;
        #pragma unroll
        for (int t = 0; t < 4; ++t)
            #pragma unroll
            for (int r = 0; r < 4; ++r)
                o[t][r] *= al;               // al is lane-scalar (per q=fr)

        // P staged as [q][kv] (stride 40): write = S^T C-layout, read = B-frag (B[k=kv][n=q])
        short4v w0, w1;
        #pragma unroll
        for (int r = 0; r < 4; ++r) { w0[r] = bf16_bits(v0[r]); w1[r] = bf16_bits(v1[r]); }
        *(short4v*)&Pw[fr * 40 + (quad << 2)]      = w0;
        *(short4v*)&Pw[fr * 40 + 16 + (quad << 2)] = w1;
        const short8 pb = *(const short8*)&Pw[fr * 40 + fk];

        // PV: A-frag = V^T (A[m=d][k=kv]) from Vt rows, contiguous 16B per lane
        #pragma unroll
        for (int t = 0; t < 4; ++t) {
            const short8 vf = *(const short8*)(Vbase + (((size_t)((t << 4) + fr)) << 11) + kv0 + fk);
            o[t] = MFMA16(vf, pb, o[t]);
        }
    };

    int c = 0;
    for (; c + 1 < nfull; c += 2) {
        chunk(c << 5,       mA, lA, oA, PwA, false);
        chunk((c + 1) << 5, mB, lB, oB, PwB, false);
    }
    if (c < nfull)
        chunk(c << 5, mA, lA, oA, PwA, false);
    chunk(nfull << 5, mA, lA, oA, PwA, true);     // diagonal (masked) chunk

    // merge streams (all lane-scalar)
    const float mm = fmaxf(mA, mB);
    const float wA = __builtin_amdgcn_exp2f(mA - mm);
    const float wB = __builtin_amdgcn_exp2f(mB - mm);
    const float linv = 1.0f / (lA * wA + lB * wB);

    // store O^T: lane owns row q=q0+fr, d = t*16+quad*4+r -> 4x 8B stores
    bf16_t* Arow = AO + (size_t)(b * SEQ + q0 + fr) * EMBED + h * HDIM;
    #pragma unroll
    for (int t = 0; t < 4; ++t) {
        short4v pk;
        #pragma unroll
        for (int r = 0; r < 4; ++r)
            pk[r] = bf16_bits((oA[t][r] * wA + oB[t][r] * wB) * linv);
        *(short4v*)(Arow + (t << 4) + (quad << 2)) = pk;
    }
}

extern "C" void kernel_launch(void* const* d_in, const int* in_sizes, int n_in,
                              void* d_out, int out_size, void* d_ws, size_t ws_size,
                              hipStream_t stream)
{
    (void)in_sizes; (void)n_in; (void)out_size; (void)ws_size;
    const float* q  = (const float*)d_in[0];
    const float* k  = (const float*)d_in[1];
    const float* v  = (const float*)d_in[2];
    const float* Wq = (const float*)d_in[3];
    const float* bq = (const float*)d_in[4];
    const float* Wk = (const float*)d_in[5];
    const float* bk = (const float*)d_in[6];
    const float* Wv = (const float*)d_in[7];
    const float* bv = (const float*)d_in[8];
    const float* Wo = (const float*)d_in[9];
    const float* bo = (const float*)d_in[10];
    // d_in[11] = attn_mask: fixed causal tril, handled analytically.

    const size_t NX = (size_t)MTOT * EMBED;   // 4M
    const size_t NW = (size_t)EMBED * EMBED;  // 1M
    bf16_t* Qx  = (bf16_t*)d_ws;
    bf16_t* Kx  = Qx  + NX;
    bf16_t* Vx  = Kx  + NX;
    bf16_t* Wqb = Vx  + NX;
    bf16_t* Wkb = Wqb + NW;
    bf16_t* Wvb = Wkb + NW;
    bf16_t* Wob = Wvb + NW;
    bf16_t* Qp  = Wob + NW;
    bf16_t* Kp  = Qp  + NX;
    bf16_t* Vtp = Kp  + NX;   // transposed: [b*1024 + d_global][s]
    bf16_t* AO  = Vtp + NX;   // total 32M bf16 = 64 MB

    dim3 blk(256);
    cvt_all<<<dim3(4096, 7), blk, 0, stream>>>(q, k, v, Wq, Wk, Wv, Wo,
                                               Qx, Kx, Vx, Wqb, Wkb, Wvb, Wob);
    qkv_proj<<<dim3(256, 1, 3), blk, 0, stream>>>(Qx, Kx, Vx, Wqb, Wkb, Wvb,
                                                  bq, bk, bv, Qp, Kp, Vtp);
    attn_causal<<<dim3(1024), blk, 0, stream>>>(Qp, Kp, Vtp, AO);
    out_proj<<<dim3(256), blk, 0, stream>>>(AO, Wob, bo, (float*)d_out);
}

// Round 6
// 335.577 us; speedup vs baseline: 1.0527x; 1.0527x over previous
//
#include <hip/hip_runtime.h>
#include <hip/hip_bf16.h>
#include <stdint.h>
#include <stddef.h>

typedef __hip_bfloat16 bf16_t;
typedef __attribute__((ext_vector_type(8))) short short8;
typedef __attribute__((ext_vector_type(4))) short short4v;
typedef __attribute__((ext_vector_type(4))) float floatx4;

#define EMBED 1024
#define NHEAD 16
#define HDIM  64
#define BATCH 2
#define SEQ   2048
#define MTOT  (BATCH*SEQ)
#define NEG_INF (-1e30f)
#define QSCALE 0.1803368801111244f   // 0.125 * log2(e): S emerges in exp2 domain

#define MFMA16(a,b,c) __builtin_amdgcn_mfma_f32_16x16x32_bf16(a,b,c,0,0,0)

static __device__ __forceinline__ short bf16_bits(float x) {
    return __builtin_bit_cast(short, __float2bfloat16(x));
}

// async global->LDS, 16B per lane; lds ptr must be wave-uniform (HW: base + lane*16)
static __device__ __forceinline__ void async_ld16(const bf16_t* g, short* l) {
    __builtin_amdgcn_global_load_lds(
        (const __attribute__((address_space(1))) void*)g,
        (__attribute__((address_space(3))) void*)l,
        16, 0, 0);
}

static __device__ __forceinline__ void store_out(float* p, float v)  { *p = v; }
static __device__ __forceinline__ void store_out(bf16_t* p, float v) { *p = __float2bfloat16(v); }

// fp32 -> bf16 (RTNE) for q,k,v (4M each) and Wq,Wk,Wv,Wo (1M each). grid.y selects tensor.
__global__ __launch_bounds__(256)
void cvt_all(const float* __restrict__ q, const float* __restrict__ k, const float* __restrict__ v,
             const float* __restrict__ wq, const float* __restrict__ wk,
             const float* __restrict__ wv, const float* __restrict__ wo,
             bf16_t* __restrict__ Qx, bf16_t* __restrict__ Kx, bf16_t* __restrict__ Vx,
             bf16_t* __restrict__ Wqb, bf16_t* __restrict__ Wkb,
             bf16_t* __restrict__ Wvb, bf16_t* __restrict__ Wob)
{
    const float* s; bf16_t* d; int n;
    switch (blockIdx.y) {
        case 0:  s = q;  d = Qx;  n = MTOT * EMBED;  break;
        case 1:  s = k;  d = Kx;  n = MTOT * EMBED;  break;
        case 2:  s = v;  d = Vx;  n = MTOT * EMBED;  break;
        case 3:  s = wq; d = Wqb; n = EMBED * EMBED; break;
        case 4:  s = wk; d = Wkb; n = EMBED * EMBED; break;
        case 5:  s = wv; d = Wvb; n = EMBED * EMBED; break;
        default: s = wo; d = Wob; n = EMBED * EMBED; break;
    }
    const int i4 = (int)blockIdx.x * 256 + (int)threadIdx.x;   // float4 index
    if (i4 * 4 < n) {
        const float4 f = ((const float4*)s)[i4];
        short4v o;
        o[0] = bf16_bits(f.x); o[1] = bf16_bits(f.y);
        o[2] = bf16_bits(f.z); o[3] = bf16_bits(f.w);
        ((short4v*)d)[i4] = o;
    }
}

// C[M,N] = A[M,K] @ W[N,K]^T + bias, bf16 in, fp32 accumulate, output scaled by oscale.
// M=4096, N=K=1024 fixed. 128x128 tile, BK=32, 256 thr (4 waves 2x2). m97 structure.
// VT=true: write output transposed per-batch as Ct[b*1024 + n][s].
template <typename OutT, bool VT>
static __device__ __forceinline__ void gemm_tile_128(
    const bf16_t* __restrict__ A, const bf16_t* __restrict__ W,
    const float* __restrict__ bias, OutT* __restrict__ C, float oscale)
{
    const int N = 1024, K = 1024;
    __shared__ alignas(16) short As[128*32];
    __shared__ alignas(16) short Bs[128*32];

    const int tid  = threadIdx.x;
    const int wave = tid >> 6;
    const int lane = tid & 63;
    const int nbn = N >> 7;                 // 8
    const int bm = (int)blockIdx.x / nbn;
    const int bn = (int)blockIdx.x % nbn;
    const int m0 = bm << 7, n0 = bn << 7;

    const int wm = ((wave >> 1) & 1) << 6;  // 0 / 64
    const int wn = (wave & 1) << 6;

    floatx4 acc[4][4] = {};

    const int srow = (wave << 5) + (lane >> 2);   // staging row within tile
    const int scol = (lane & 3) << 3;             // element col: 0,8,16,24
    const bf16_t* gA = A + (size_t)(m0 + srow) * K + scol;
    const bf16_t* gB = W + (size_t)(n0 + srow) * K + scol;
    short* lA0 = &As[(wave << 10)];
    short* lA1 = &As[(wave << 10) + 512];
    short* lB0 = &Bs[(wave << 10)];
    short* lB1 = &Bs[(wave << 10) + 512];

    const int fr = lane & 15;
    const int fk = (lane >> 4) << 3;

    for (int k0 = 0; k0 < K; k0 += 32) {
        __syncthreads();
        async_ld16(gA,                  lA0);
        async_ld16(gA + (size_t)16 * K, lA1);
        async_ld16(gB,                  lB0);
        async_ld16(gB + (size_t)16 * K, lB1);
        gA += 32; gB += 32;
        __syncthreads();                      // drains vmcnt before barrier (m97-verified)

        short8 af[4], bfr[4];
        #pragma unroll
        for (int i = 0; i < 4; ++i)
            af[i] = *(const short8*)&As[(wm + (i << 4) + fr) * 32 + fk];
        #pragma unroll
        for (int j = 0; j < 4; ++j)
            bfr[j] = *(const short8*)&Bs[(wn + (j << 4) + fr) * 32 + fk];
        #pragma unroll
        for (int i = 0; i < 4; ++i)
            #pragma unroll
            for (int j = 0; j < 4; ++j)
                acc[i][j] = MFMA16(af[i], bfr[j], acc[i][j]);
    }

    // epilogue: C/D layout col=lane&15, row=quad*4+r
    const int q4 = (lane >> 4) << 2;
    #pragma unroll
    for (int j = 0; j < 4; ++j) {
        const int n = n0 + wn + (j << 4) + fr;
        const float bv = bias[n];
        #pragma unroll
        for (int i = 0; i < 4; ++i) {
            const int mb = m0 + wm + (i << 4) + q4;
            if (VT) {
                const int bb = mb >> 11, ss = mb & 2047;
                short4v pk;
                #pragma unroll
                for (int r = 0; r < 4; ++r)
                    pk[r] = bf16_bits((acc[i][j][r] + bv) * oscale);
                *(short4v*)((bf16_t*)C + ((size_t)(bb * 1024 + n) << 11) + ss) = pk;
            } else {
                #pragma unroll
                for (int r = 0; r < 4; ++r)
                    store_out(&C[(size_t)(mb + r) * N + n], (acc[i][j][r] + bv) * oscale);
            }
        }
    }
}

__global__ __launch_bounds__(256)
void qkv_proj(const bf16_t* __restrict__ xq, const bf16_t* __restrict__ xk,
              const bf16_t* __restrict__ xv,
              const bf16_t* __restrict__ Wq, const bf16_t* __restrict__ Wk,
              const bf16_t* __restrict__ Wv,
              const float* __restrict__ bq, const float* __restrict__ bk,
              const float* __restrict__ bv,
              bf16_t* __restrict__ Qp, bf16_t* __restrict__ Kp, bf16_t* __restrict__ Vtp)
{
    if (blockIdx.z == 0)      gemm_tile_128<bf16_t, false>(xq, Wq, bq, Qp, QSCALE);  // Q pre-scaled
    else if (blockIdx.z == 1) gemm_tile_128<bf16_t, false>(xk, Wk, bk, Kp, 1.0f);
    else                      gemm_tile_128<bf16_t, true >(xv, Wv, bv, Vtp, 1.0f);
}

__global__ __launch_bounds__(256)
void out_proj(const bf16_t* __restrict__ AO, const bf16_t* __restrict__ Wo,
              const float* __restrict__ bo, float* __restrict__ out)
{
    gemm_tile_128<float, false>(AO, Wo, bo, out, 1.0f);
}

// Flash attention, causal. S^T (D = K·Q^T) and O^T (D = V^T·P^T): one q-row per lane
// (q = lane&15), softmax state + rescale are lane-scalars. P round-trips through
// wave-local LDS [16 q][stride 40] (write = S^T C-layout, read = B-frag; stride 40
// shorts = conflict-free for both). Single accumulator stream (R5 lesson: ILP via
// dual streams costs VGPR/occupancy and loses — TLP is the lever).
// KV-SPLIT: each q-tile is worked by a WAVE PAIR — even chunks / odd chunks, each
// with independent (m,l,O) online-softmax state, merged at the end via LDS + one
// uniform __syncthreads. Grid 2048 blocks = 8 blocks/CU = 32 waves/CU target.
// Block g of head bh: waves {0,1} -> tile g, waves {2,3} -> tile 127-g (constant work).
__global__ __launch_bounds__(256, 8)   // pin <=64 VGPR: need 8 waves/SIMD resident
void attn_causal(const bf16_t* __restrict__ Qp, const bf16_t* __restrict__ Kp,
                 const bf16_t* __restrict__ Vt, bf16_t* __restrict__ AO)
{
    __shared__ alignas(16) short Pbuf[4][16 * 40];       // per-wave P staging, 1280 B
    __shared__ alignas(16) float Obuf[2][64 * 16];       // per-pair O^T dump, 4 KB
    __shared__ float Mbuf[2][64], Lbuf[2][64];

    const int tid  = threadIdx.x;
    const int wave = tid >> 6;
    const int lane = tid & 63;
    const int g  = (int)blockIdx.x & 63;          // 0..63
    const int bh = (int)blockIdx.x >> 6;          // 0..31
    const int b  = bh >> 4, h = bh & 15;
    const int pair = wave >> 1;                   // 0,1
    const int p    = wave & 1;                    // parity within pair
    const int tile = pair ? (127 - g) : g;
    const int q0 = tile << 4;

    const int fr   = lane & 15;
    const int quad = lane >> 4;
    const int fk   = quad << 3;

    // Q B-frags (B[k=d][n=q]): lane holds Q[q0+fr][fk+j] (+32)
    const bf16_t* Qrow = Qp + (size_t)(b * SEQ + q0 + fr) * EMBED + h * HDIM;
    const short8 aq0 = *(const short8*)(Qrow + fk);
    const short8 aq1 = *(const short8*)(Qrow + 32 + fk);

    const bf16_t* Kbase = Kp + (size_t)(b * SEQ) * EMBED + h * HDIM;
    const bf16_t* Vbase = Vt + ((size_t)(b * 1024 + h * HDIM) << 11);

    floatx4 o[4] = {};            // O^T[d=t*16+quad*4+r][q=fr]
    float m = NEG_INF, l = 0.f;   // lane-scalar (one q-row per lane)

    short* Pw = &Pbuf[wave][0];
    const int nfull = q0 >> 5;    // fully-unmasked 32-kv chunks; then 1 masked (diagonal)

    auto chunk = [&](int kv0, bool masked) {
        // K A-frags (A[m=kv][k=d]): lane holds K[kv0+(sub*16)+fr][fk+j]
        const bf16_t* Kr0 = Kbase + (size_t)(kv0 + fr) * EMBED;
        const bf16_t* Kr1 = Kr0 + (size_t)16 * EMBED;
        const short8 k00 = *(const short8*)(Kr0 + fk);
        const short8 k01 = *(const short8*)(Kr0 + 32 + fk);
        const short8 k10 = *(const short8*)(Kr1 + fk);
        const short8 k11 = *(const short8*)(Kr1 + 32 + fk);

        floatx4 s0 = {}, s1 = {};
        s0 = MFMA16(k00, aq0, s0);
        s0 = MFMA16(k01, aq1, s0);
        s1 = MFMA16(k10, aq0, s1);
        s1 = MFMA16(k11, aq1, s1);

        // S^T layout: lane holds S[kv0 + quad*4+r (+16)][q0+fr], already exp2-domain
        float v0[4], v1[4], mx = NEG_INF;
        #pragma unroll
        for (int r = 0; r < 4; ++r) {
            float a = s0[r], bb = s1[r];
            if (masked) {
                const int q = q0 + fr, kva = kv0 + (quad << 2) + r;
                if (kva > q)      a  = NEG_INF;
                if (kva + 16 > q) bb = NEG_INF;
            }
            v0[r] = a; v1[r] = bb;
            mx = fmaxf(mx, fmaxf(a, bb));
        }
        mx = fmaxf(mx, __shfl_xor(mx, 16, 64));
        mx = fmaxf(mx, __shfl_xor(mx, 32, 64));

        const float mnew = fmaxf(m, mx);
        const float al = __builtin_amdgcn_exp2f(m - mnew);
        m = mnew;
        float ls = 0.f;
        #pragma unroll
        for (int r = 0; r < 4; ++r) {
            v0[r] = __builtin_amdgcn_exp2f(v0[r] - mnew);
            v1[r] = __builtin_amdgcn_exp2f(v1[r] - mnew);
            ls += v0[r] + v1[r];
        }
        ls += __shfl_xor(ls, 16, 64);
        ls += __shfl_xor(ls, 32, 64);
        l = l * al + ls;
        #pragma unroll
        for (int t = 0; t < 4; ++t)
            #pragma unroll
            for (int r = 0; r < 4; ++r)
                o[t][r] *= al;               // al is lane-scalar (per q=fr)

        // P staged as [q][kv] stride 40: write = S^T C-layout, read = B-frag (B[k=kv][n=q])
        short4v w0, w1;
        #pragma unroll
        for (int r = 0; r < 4; ++r) { w0[r] = bf16_bits(v0[r]); w1[r] = bf16_bits(v1[r]); }
        *(short4v*)&Pw[fr * 40 + (quad << 2)]      = w0;
        *(short4v*)&Pw[fr * 40 + 16 + (quad << 2)] = w1;
        const short8 pb = *(const short8*)&Pw[fr * 40 + fk];

        // PV: A-frag = V^T (A[m=d][k=kv]) from Vt rows, contiguous 16B per lane
        #pragma unroll
        for (int t = 0; t < 4; ++t) {
            const short8 vf = *(const short8*)(Vbase + (((size_t)((t << 4) + fr)) << 11) + kv0 + fk);
            o[t] = MFMA16(vf, pb, o[t]);
        }
    };

    // parity-split KV range: wave p takes chunks c == p (mod 2); diagonal keeps parity
    for (int c = p; c < nfull; c += 2)
        chunk(c << 5, false);
    if ((nfull & 1) == p)
        chunk(nfull << 5, true);

    // merge wave pair via LDS (single uniform barrier)
    if (p == 0) {
        #pragma unroll
        for (int t = 0; t < 4; ++t)
            *(floatx4*)&Obuf[pair][(lane << 4) + (t << 2)] = o[t];
        Mbuf[pair][lane] = m;
        Lbuf[pair][lane] = l;
    }
    __syncthreads();
    if (p == 1) {
        const float mo = Mbuf[pair][lane];
        const float lo = Lbuf[pair][lane];
        const float mm = fmaxf(m, mo);
        const float wS = __builtin_amdgcn_exp2f(m - mm);    // self
        const float wO = __builtin_amdgcn_exp2f(mo - mm);   // other (even wave)
        const float linv = 1.0f / (l * wS + lo * wO);

        bf16_t* Arow = AO + (size_t)(b * SEQ + q0 + fr) * EMBED + h * HDIM;
        #pragma unroll
        for (int t = 0; t < 4; ++t) {
            const floatx4 oo = *(const floatx4*)&Obuf[pair][(lane << 4) + (t << 2)];
            short4v pk;
            #pragma unroll
            for (int r = 0; r < 4; ++r)
                pk[r] = bf16_bits((o[t][r] * wS + oo[r] * wO) * linv);
            *(short4v*)(Arow + (t << 4) + (quad << 2)) = pk;
        }
    }
}

extern "C" void kernel_launch(void* const* d_in, const int* in_sizes, int n_in,
                              void* d_out, int out_size, void* d_ws, size_t ws_size,
                              hipStream_t stream)
{
    (void)in_sizes; (void)n_in; (void)out_size; (void)ws_size;
    const float* q  = (const float*)d_in[0];
    const float* k  = (const float*)d_in[1];
    const float* v  = (const float*)d_in[2];
    const float* Wq = (const float*)d_in[3];
    const float* bq = (const float*)d_in[4];
    const float* Wk = (const float*)d_in[5];
    const float* bk = (const float*)d_in[6];
    const float* Wv = (const float*)d_in[7];
    const float* bv = (const float*)d_in[8];
    const float* Wo = (const float*)d_in[9];
    const float* bo = (const float*)d_in[10];
    // d_in[11] = attn_mask: fixed causal tril, handled analytically.

    const size_t NX = (size_t)MTOT * EMBED;   // 4M
    const size_t NW = (size_t)EMBED * EMBED;  // 1M
    bf16_t* Qx  = (bf16_t*)d_ws;
    bf16_t* Kx  = Qx  + NX;
    bf16_t* Vx  = Kx  + NX;
    bf16_t* Wqb = Vx  + NX;
    bf16_t* Wkb = Wqb + NW;
    bf16_t* Wvb = Wkb + NW;
    bf16_t* Wob = Wvb + NW;
    bf16_t* Qp  = Wob + NW;
    bf16_t* Kp  = Qp  + NX;
    bf16_t* Vtp = Kp  + NX;   // transposed: [b*1024 + d_global][s]
    bf16_t* AO  = Vtp + NX;   // total 32M bf16 = 64 MB

    dim3 blk(256);
    cvt_all<<<dim3(4096, 7), blk, 0, stream>>>(q, k, v, Wq, Wk, Wv, Wo,
                                               Qx, Kx, Vx, Wqb, Wkb, Wvb, Wob);
    qkv_proj<<<dim3(256, 1, 3), blk, 0, stream>>>(Qx, Kx, Vx, Wqb, Wkb, Wvb,
                                                  bq, bk, bv, Qp, Kp, Vtp);
    attn_causal<<<dim3(2048), blk, 0, stream>>>(Qp, Kp, Vtp, AO);
    out_proj<<<dim3(256), blk, 0, stream>>>(AO, Wob, bo, (float*)d_out);
}

// Round 7
// 330.381 us; speedup vs baseline: 1.0692x; 1.0157x over previous
//
#include <hip/hip_runtime.h>
#include <hip/hip_bf16.h>
#include <stdint.h>
#include <stddef.h>

typedef __hip_bfloat16 bf16_t;
typedef __attribute__((ext_vector_type(8))) short short8;
typedef __attribute__((ext_vector_type(4))) short short4v;
typedef __attribute__((ext_vector_type(4))) float floatx4;

#define EMBED 1024
#define NHEAD 16
#define HDIM  64
#define BATCH 2
#define SEQ   2048
#define MTOT  (BATCH*SEQ)
#define NEG_INF (-1e30f)
#define QSCALE 0.1803368801111244f   // 0.125 * log2(e): S emerges in exp2 domain

#define MFMA16(a,b,c) __builtin_amdgcn_mfma_f32_16x16x32_bf16(a,b,c,0,0,0)

static __device__ __forceinline__ short bf16_bits(float x) {
    return __builtin_bit_cast(short, __float2bfloat16(x));
}

// async global->LDS, 16B per lane; lds ptr must be wave-uniform (HW: base + lane*16)
static __device__ __forceinline__ void async_ld16(const bf16_t* g, short* l) {
    __builtin_amdgcn_global_load_lds(
        (const __attribute__((address_space(1))) void*)g,
        (__attribute__((address_space(3))) void*)l,
        16, 0, 0);
}

static __device__ __forceinline__ void store_out(float* p, float v)  { *p = v; }
static __device__ __forceinline__ void store_out(bf16_t* p, float v) { *p = __float2bfloat16(v); }

// fp32 -> bf16 (RTNE) for q,k,v (4M each) and Wq,Wk,Wv,Wo (1M each). grid.y selects tensor.
__global__ __launch_bounds__(256)
void cvt_all(const float* __restrict__ q, const float* __restrict__ k, const float* __restrict__ v,
             const float* __restrict__ wq, const float* __restrict__ wk,
             const float* __restrict__ wv, const float* __restrict__ wo,
             bf16_t* __restrict__ Qx, bf16_t* __restrict__ Kx, bf16_t* __restrict__ Vx,
             bf16_t* __restrict__ Wqb, bf16_t* __restrict__ Wkb,
             bf16_t* __restrict__ Wvb, bf16_t* __restrict__ Wob)
{
    const float* s; bf16_t* d; int n;
    switch (blockIdx.y) {
        case 0:  s = q;  d = Qx;  n = MTOT * EMBED;  break;
        case 1:  s = k;  d = Kx;  n = MTOT * EMBED;  break;
        case 2:  s = v;  d = Vx;  n = MTOT * EMBED;  break;
        case 3:  s = wq; d = Wqb; n = EMBED * EMBED; break;
        case 4:  s = wk; d = Wkb; n = EMBED * EMBED; break;
        case 5:  s = wv; d = Wvb; n = EMBED * EMBED; break;
        default: s = wo; d = Wob; n = EMBED * EMBED; break;
    }
    const int i4 = (int)blockIdx.x * 256 + (int)threadIdx.x;   // float4 index
    if (i4 * 4 < n) {
        const float4 f = ((const float4*)s)[i4];
        short4v o;
        o[0] = bf16_bits(f.x); o[1] = bf16_bits(f.y);
        o[2] = bf16_bits(f.z); o[3] = bf16_bits(f.w);
        ((short4v*)d)[i4] = o;
    }
}

// C[M,N] = A[M,K] @ W[N,K]^T + bias, bf16 in, fp32 accumulate, output scaled by oscale.
// M=4096, N=K=1024 fixed. 128x128 tile, BK=32, 256 thr (4 waves 2x2). m97 structure.
// VT=true: write output transposed per-batch as Ct[b*1024 + n][s].
template <typename OutT, bool VT>
static __device__ __forceinline__ void gemm_tile_128(
    const bf16_t* __restrict__ A, const bf16_t* __restrict__ W,
    const float* __restrict__ bias, OutT* __restrict__ C, float oscale)
{
    const int N = 1024, K = 1024;
    __shared__ alignas(16) short As[128*32];
    __shared__ alignas(16) short Bs[128*32];

    const int tid  = threadIdx.x;
    const int wave = tid >> 6;
    const int lane = tid & 63;
    const int nbn = N >> 7;                 // 8
    const int bm = (int)blockIdx.x / nbn;
    const int bn = (int)blockIdx.x % nbn;
    const int m0 = bm << 7, n0 = bn << 7;

    const int wm = ((wave >> 1) & 1) << 6;  // 0 / 64
    const int wn = (wave & 1) << 6;

    floatx4 acc[4][4] = {};

    const int srow = (wave << 5) + (lane >> 2);   // staging row within tile
    const int scol = (lane & 3) << 3;             // element col: 0,8,16,24
    const bf16_t* gA = A + (size_t)(m0 + srow) * K + scol;
    const bf16_t* gB = W + (size_t)(n0 + srow) * K + scol;
    short* lA0 = &As[(wave << 10)];
    short* lA1 = &As[(wave << 10) + 512];
    short* lB0 = &Bs[(wave << 10)];
    short* lB1 = &Bs[(wave << 10) + 512];

    const int fr = lane & 15;
    const int fk = (lane >> 4) << 3;

    for (int k0 = 0; k0 < K; k0 += 32) {
        __syncthreads();
        async_ld16(gA,                  lA0);
        async_ld16(gA + (size_t)16 * K, lA1);
        async_ld16(gB,                  lB0);
        async_ld16(gB + (size_t)16 * K, lB1);
        gA += 32; gB += 32;
        __syncthreads();                      // drains vmcnt before barrier (m97-verified)

        short8 af[4], bfr[4];
        #pragma unroll
        for (int i = 0; i < 4; ++i)
            af[i] = *(const short8*)&As[(wm + (i << 4) + fr) * 32 + fk];
        #pragma unroll
        for (int j = 0; j < 4; ++j)
            bfr[j] = *(const short8*)&Bs[(wn + (j << 4) + fr) * 32 + fk];
        #pragma unroll
        for (int i = 0; i < 4; ++i)
            #pragma unroll
            for (int j = 0; j < 4; ++j)
                acc[i][j] = MFMA16(af[i], bfr[j], acc[i][j]);
    }

    // epilogue: C/D layout col=lane&15, row=quad*4+r
    const int q4 = (lane >> 4) << 2;
    #pragma unroll
    for (int j = 0; j < 4; ++j) {
        const int n = n0 + wn + (j << 4) + fr;
        const float bv = bias[n];
        #pragma unroll
        for (int i = 0; i < 4; ++i) {
            const int mb = m0 + wm + (i << 4) + q4;
            if (VT) {
                const int bb = mb >> 11, ss = mb & 2047;
                short4v pk;
                #pragma unroll
                for (int r = 0; r < 4; ++r)
                    pk[r] = bf16_bits((acc[i][j][r] + bv) * oscale);
                *(short4v*)((bf16_t*)C + ((size_t)(bb * 1024 + n) << 11) + ss) = pk;
            } else {
                #pragma unroll
                for (int r = 0; r < 4; ++r)
                    store_out(&C[(size_t)(mb + r) * N + n], (acc[i][j][r] + bv) * oscale);
            }
        }
    }
}

__global__ __launch_bounds__(256)
void qkv_proj(const bf16_t* __restrict__ xq, const bf16_t* __restrict__ xk,
              const bf16_t* __restrict__ xv,
              const bf16_t* __restrict__ Wq, const bf16_t* __restrict__ Wk,
              const bf16_t* __restrict__ Wv,
              const float* __restrict__ bq, const float* __restrict__ bk,
              const float* __restrict__ bv,
              bf16_t* __restrict__ Qp, bf16_t* __restrict__ Kp, bf16_t* __restrict__ Vtp)
{
    if (blockIdx.z == 0)      gemm_tile_128<bf16_t, false>(xq, Wq, bq, Qp, QSCALE);  // Q pre-scaled
    else if (blockIdx.z == 1) gemm_tile_128<bf16_t, false>(xk, Wk, bk, Kp, 1.0f);
    else                      gemm_tile_128<bf16_t, true >(xv, Wv, bv, Vtp, 1.0f);
}

__global__ __launch_bounds__(256)
void out_proj(const bf16_t* __restrict__ AO, const bf16_t* __restrict__ Wo,
              const float* __restrict__ bo, float* __restrict__ out)
{
    gemm_tile_128<float, false>(AO, Wo, bo, out, 1.0f);
}

// Flash attention, causal. S^T (D = K·Q^T) and O^T (D = V^T·P^T): one q-row per lane
// (q = lane&15); softmax m is lane-scalar; l is accumulated BY MFMA (all-ones A-frag
// into a 5th accumulator o5 — the alpha-rescale recurrence applies to it identically,
// and l is exactly consistent with the bf16-rounded P used for O). P round-trips
// through wave-local LDS [16 q][stride 40] (conflict-free both ways).
// KV-SPLIT: wave pair = one q-tile, even/odd chunks, merged via LDS + one barrier.
// XCD SWIZZLE: blockIdx.x = (bh&7) + 8*(g + 64*(bh>>3)) — with round-robin
// block->XCD assignment (%8), all 64 blocks of a head stay on ONE XCD, so its
// 0.5 MB K/V working set lives in that XCD's L2 (4 heads/XCD = 2 MB < 4 MB).
__global__ __launch_bounds__(256, 8)   // pin <=64 VGPR: 8 waves/SIMD resident
void attn_causal(const bf16_t* __restrict__ Qp, const bf16_t* __restrict__ Kp,
                 const bf16_t* __restrict__ Vt, bf16_t* __restrict__ AO)
{
    __shared__ alignas(16) short Pbuf[4][16 * 40];       // per-wave P staging, 1280 B
    __shared__ alignas(16) float Obuf[2][64 * 16];       // per-pair O^T dump, 4 KB
    __shared__ float Mbuf[2][64], Lbuf[2][64];

    const int tid  = threadIdx.x;
    const int wave = tid >> 6;
    const int lane = tid & 63;
    const int d  = (int)blockIdx.x;
    const int bh = (d & 7) | ((d >> 9) << 3);     // xcd-pinned head index 0..31
    const int g  = (d >> 3) & 63;                 // 0..63
    const int b  = bh >> 4, h = bh & 15;
    const int pair = wave >> 1;                   // 0,1
    const int p    = wave & 1;                    // parity within pair
    const int tile = pair ? (127 - g) : g;
    const int q0 = tile << 4;

    const int fr   = lane & 15;
    const int quad = lane >> 4;
    const int fk   = quad << 3;

    // Q B-frags (B[k=d][n=q]): lane holds Q[q0+fr][fk+j] (+32)
    const bf16_t* Qrow = Qp + (size_t)(b * SEQ + q0 + fr) * EMBED + h * HDIM;
    const short8 aq0 = *(const short8*)(Qrow + fk);
    const short8 aq1 = *(const short8*)(Qrow + 32 + fk);

    const bf16_t* Kbase = Kp + (size_t)(b * SEQ) * EMBED + h * HDIM;
    const bf16_t* Vbase = Vt + ((size_t)(b * 1024 + h * HDIM) << 11);

    short8 ones;                  // all-ones A-frag for the l-row MFMA
    #pragma unroll
    for (int j = 0; j < 8; ++j) ones[j] = (short)0x3F80;   // bf16 1.0

    floatx4 o[4] = {};            // O^T[d=t*16+quad*4+r][q=fr]
    floatx4 o5 = {};              // l accumulator: every row = l(q=fr)
    float m = NEG_INF;            // lane-scalar (one q-row per lane)

    short* Pw = &Pbuf[wave][0];
    const int nfull = q0 >> 5;    // fully-unmasked 32-kv chunks; then 1 masked (diagonal)

    auto chunk = [&](int kv0, bool masked) {
        // V A-frags first: independent of QK/softmax -> issue early, latency covered
        short8 vf[4];
        #pragma unroll
        for (int t = 0; t < 4; ++t)
            vf[t] = *(const short8*)(Vbase + (((size_t)((t << 4) + fr)) << 11) + kv0 + fk);

        // K A-frags (A[m=kv][k=d]): lane holds K[kv0+(sub*16)+fr][fk+j]
        const bf16_t* Kr0 = Kbase + (size_t)(kv0 + fr) * EMBED;
        const bf16_t* Kr1 = Kr0 + (size_t)16 * EMBED;
        const short8 k00 = *(const short8*)(Kr0 + fk);
        const short8 k01 = *(const short8*)(Kr0 + 32 + fk);
        const short8 k10 = *(const short8*)(Kr1 + fk);
        const short8 k11 = *(const short8*)(Kr1 + 32 + fk);

        floatx4 s0 = {}, s1 = {};
        s0 = MFMA16(k00, aq0, s0);
        s0 = MFMA16(k01, aq1, s0);
        s1 = MFMA16(k10, aq0, s1);
        s1 = MFMA16(k11, aq1, s1);

        // S^T layout: lane holds S[kv0 + quad*4+r (+16)][q0+fr], already exp2-domain
        float v0[4], v1[4], mx = NEG_INF;
        #pragma unroll
        for (int r = 0; r < 4; ++r) {
            float a = s0[r], bb = s1[r];
            if (masked) {
                const int q = q0 + fr, kva = kv0 + (quad << 2) + r;
                if (kva > q)      a  = NEG_INF;
                if (kva + 16 > q) bb = NEG_INF;
            }
            v0[r] = a; v1[r] = bb;
            mx = fmaxf(mx, fmaxf(a, bb));
        }
        mx = fmaxf(mx, __shfl_xor(mx, 16, 64));
        mx = fmaxf(mx, __shfl_xor(mx, 32, 64));

        const float mnew = fmaxf(m, mx);
        const float al = __builtin_amdgcn_exp2f(m - mnew);
        m = mnew;
        #pragma unroll
        for (int r = 0; r < 4; ++r) {
            v0[r] = __builtin_amdgcn_exp2f(v0[r] - mnew);
            v1[r] = __builtin_amdgcn_exp2f(v1[r] - mnew);
        }
        #pragma unroll
        for (int t = 0; t < 4; ++t)
            #pragma unroll
            for (int r = 0; r < 4; ++r)
                o[t][r] *= al;               // al is lane-scalar (per q=fr)
        #pragma unroll
        for (int r = 0; r < 4; ++r)
            o5[r] *= al;                     // l follows the same recurrence

        // P staged as [q][kv] stride 40: write = S^T C-layout, read = B-frag (B[k=kv][n=q])
        short4v w0, w1;
        #pragma unroll
        for (int r = 0; r < 4; ++r) { w0[r] = bf16_bits(v0[r]); w1[r] = bf16_bits(v1[r]); }
        *(short4v*)&Pw[fr * 40 + (quad << 2)]      = w0;
        *(short4v*)&Pw[fr * 40 + 16 + (quad << 2)] = w1;
        const short8 pb = *(const short8*)&Pw[fr * 40 + fk];

        o5 = MFMA16(ones, pb, o5);           // l += column-sums of P^T
        #pragma unroll
        for (int t = 0; t < 4; ++t)
            o[t] = MFMA16(vf[t], pb, o[t]);
    };

    // parity-split KV range: wave p takes chunks c == p (mod 2); diagonal keeps parity
    for (int c = p; c < nfull; c += 2)
        chunk(c << 5, false);
    if ((nfull & 1) == p)
        chunk(nfull << 5, true);

    const float l = o5[0];                   // all rows of o5 equal l(q=fr)

    // merge wave pair via LDS (single uniform barrier)
    if (p == 0) {
        #pragma unroll
        for (int t = 0; t < 4; ++t)
            *(floatx4*)&Obuf[pair][(lane << 4) + (t << 2)] = o[t];
        Mbuf[pair][lane] = m;
        Lbuf[pair][lane] = l;
    }
    __syncthreads();
    if (p == 1) {
        const float mo = Mbuf[pair][lane];
        const float lo = Lbuf[pair][lane];
        const float mm = fmaxf(m, mo);
        const float wS = __builtin_amdgcn_exp2f(m - mm);    // self
        const float wO = __builtin_amdgcn_exp2f(mo - mm);   // other (even wave)
        const float linv = 1.0f / (l * wS + lo * wO);

        bf16_t* Arow = AO + (size_t)(b * SEQ + q0 + fr) * EMBED + h * HDIM;
        #pragma unroll
        for (int t = 0; t < 4; ++t) {
            const floatx4 oo = *(const floatx4*)&Obuf[pair][(lane << 4) + (t << 2)];
            short4v pk;
            #pragma unroll
            for (int r = 0; r < 4; ++r)
                pk[r] = bf16_bits((o[t][r] * wS + oo[r] * wO) * linv);
            *(short4v*)(Arow + (t << 4) + (quad << 2)) = pk;
        }
    }
}

extern "C" void kernel_launch(void* const* d_in, const int* in_sizes, int n_in,
                              void* d_out, int out_size, void* d_ws, size_t ws_size,
                              hipStream_t stream)
{
    (void)in_sizes; (void)n_in; (void)out_size; (void)ws_size;
    const float* q  = (const float*)d_in[0];
    const float* k  = (const float*)d_in[1];
    const float* v  = (const float*)d_in[2];
    const float* Wq = (const float*)d_in[3];
    const float* bq = (const float*)d_in[4];
    const float* Wk = (const float*)d_in[5];
    const float* bk = (const float*)d_in[6];
    const float* Wv = (const float*)d_in[7];
    const float* bv = (const float*)d_in[8];
    const float* Wo = (const float*)d_in[9];
    const float* bo = (const float*)d_in[10];
    // d_in[11] = attn_mask: fixed causal tril, handled analytically.

    const size_t NX = (size_t)MTOT * EMBED;   // 4M
    const size_t NW = (size_t)EMBED * EMBED;  // 1M
    bf16_t* Qx  = (bf16_t*)d_ws;
    bf16_t* Kx  = Qx  + NX;
    bf16_t* Vx  = Kx  + NX;
    bf16_t* Wqb = Vx  + NX;
    bf16_t* Wkb = Wqb + NW;
    bf16_t* Wvb = Wkb + NW;
    bf16_t* Wob = Wvb + NW;
    bf16_t* Qp  = Wob + NW;
    bf16_t* Kp  = Qp  + NX;
    bf16_t* Vtp = Kp  + NX;   // transposed: [b*1024 + d_global][s]
    bf16_t* AO  = Vtp + NX;   // total 32M bf16 = 64 MB

    dim3 blk(256);
    cvt_all<<<dim3(4096, 7), blk, 0, stream>>>(q, k, v, Wq, Wk, Wv, Wo,
                                               Qx, Kx, Vx, Wqb, Wkb, Wvb, Wob);
    qkv_proj<<<dim3(256, 1, 3), blk, 0, stream>>>(Qx, Kx, Vx, Wqb, Wkb, Wvb,
                                                  bq, bk, bv, Qp, Kp, Vtp);
    attn_causal<<<dim3(2048), blk, 0, stream>>>(Qp, Kp, Vtp, AO);
    out_proj<<<dim3(256), blk, 0, stream>>>(AO, Wob, bo, (float*)d_out);
}